// Round 1
// baseline (169.858 us; speedup 1.0000x reference)
//
#include <hip/hip_runtime.h>
#include <cstdint>
#include <cstddef>

#define Bb 128
#define Dd 512
#define Hh 512
#define KE 16

typedef unsigned short u16;
typedef unsigned int u32;
typedef __bf16 bf16x8 __attribute__((ext_vector_type(8)));
typedef float f32x4 __attribute__((ext_vector_type(4)));

union U8 { u16 h[8]; uint4 v; };

__device__ __forceinline__ u16 f2bf(float f) {
  u32 u = __float_as_uint(f);
  u32 r = (u + 0x7fffu + ((u >> 16) & 1u)) >> 16;  // round-to-nearest-even
  return (u16)r;
}

// ---------------------------------------------------------------- prep
// part A: xu[k][b][d] = bf16(u[b,k]*x[b,d])   (16*128*512 elems, 8/thread)
// part B: zero yx[3][128][512] accumulators
// part C: dW[bank][k][h] = Wh{bank}[k][h][h]  (diagonals)
__global__ __launch_bounds__(256) void prep_kernel(
    const float* __restrict__ x, const float* __restrict__ u,
    const float* __restrict__ Whr, const float* __restrict__ Whz,
    const float* __restrict__ Whn,
    u16* __restrict__ xu, float* __restrict__ yx, float* __restrict__ dW)
{
  int t = blockIdx.x * 256 + threadIdx.x;
  if (t < 131072) {
    int d8 = t & 63;
    int rest = t >> 6;
    int b = rest & 127;
    int k = rest >> 7;
    float uk = u[b * KE + k];
    const float4* xp = (const float4*)(x + b * Dd + d8 * 8);
    float4 x0 = xp[0], x1 = xp[1];
    U8 o;
    o.h[0] = f2bf(uk * x0.x); o.h[1] = f2bf(uk * x0.y);
    o.h[2] = f2bf(uk * x0.z); o.h[3] = f2bf(uk * x0.w);
    o.h[4] = f2bf(uk * x1.x); o.h[5] = f2bf(uk * x1.y);
    o.h[6] = f2bf(uk * x1.z); o.h[7] = f2bf(uk * x1.w);
    *(uint4*)(xu + ((k * Bb + b) * Dd + d8 * 8)) = o.v;
  } else if (t < 131072 + 49152) {
    int i = t - 131072;
    ((float4*)yx)[i] = make_float4(0.f, 0.f, 0.f, 0.f);
  } else if (t < 131072 + 49152 + 24576) {
    int i = t - (131072 + 49152);
    int h = i & 511;
    int k = (i >> 9) & 15;
    int bank = i >> 13;
    const float* Wp = bank == 0 ? Whr : (bank == 1 ? Whz : Whn);
    dW[i] = Wp[(size_t)k * Hh * Hh + h * (Hh + 1)];
  }
}

// ---------------------------------------------------------------- gemm
// grid = 192: bid = ((ht*3 + bank)<<4) | k   (k in low bits -> same-k blocks
// share an XCD for xu L2 locality).  Block tile: M=128(b) x N=128(h),
// contraction D=512 in 8 chunks of 64.  4 waves, 64x64 wave tiles,
// mfma_f32_16x16x32_bf16, double-buffered LDS with XOR-16B swizzle.
__global__ __launch_bounds__(256) void gemm_kernel(
    const float* __restrict__ Wxr, const float* __restrict__ Wxz,
    const float* __restrict__ Wxn,
    const u16* __restrict__ xu, float* __restrict__ yx)
{
  int bid = blockIdx.x;
  int k = bid & 15;
  int rem = bid >> 4;          // 0..11
  int bank = rem % 3;
  int ht = rem / 3;            // 0..3

  const float* Wsrc = (bank == 0 ? Wxr : (bank == 1 ? Wxz : Wxn));
  const float* Wp = Wsrc + (size_t)k * Hh * Dd + (size_t)ht * 128 * Dd;
  const u16* Ap = xu + k * Bb * Dd;
  float* yp = yx + bank * Bb * Hh;

  __shared__ __align__(16) u16 lA[2][128 * 64];   // 16KB x2
  __shared__ __align__(16) u16 lB[2][128 * 64];   // 16KB x2

  int tid = threadIdx.x;
  int lane = tid & 63;
  int wave = tid >> 6;
  int wm = wave >> 1;
  int wn = wave & 1;

  // staging maps
  int ar = tid >> 1;            // 0..127
  int ac = (tid & 1) * 32;      // 0 / 32  (u16 elems)
  int br = tid >> 2;            // 0..63
  int bc = (tid & 3) * 16;      // 0/16/32/48 (f32 elems)

  uint4 aL[4];
  float4 bL[2][4];

  f32x4 acc[4][4];
#pragma unroll
  for (int i = 0; i < 4; ++i)
#pragma unroll
    for (int j = 0; j < 4; ++j) acc[i][j] = (f32x4){0.f, 0.f, 0.f, 0.f};

  auto LOAD = [&](int c) {
    int d0 = c * 64;
#pragma unroll
    for (int q = 0; q < 4; ++q)
      aL[q] = *(const uint4*)(Ap + ar * Dd + d0 + ac + 8 * q);
#pragma unroll
    for (int p = 0; p < 2; ++p)
#pragma unroll
      for (int q = 0; q < 4; ++q)
        bL[p][q] = *(const float4*)(Wp + (br + 64 * p) * Dd + d0 + bc + 4 * q);
  };

  auto STORE = [&](int nb) {
#pragma unroll
    for (int q = 0; q < 4; ++q) {
      int slot = ((ac >> 3) + q) ^ (ar & 7);
      *(uint4*)((char*)lA[nb] + ar * 128 + slot * 16) = aL[q];
    }
#pragma unroll
    for (int p = 0; p < 2; ++p) {
      int row = br + 64 * p;
      U8 g0, g1;
      g0.h[0] = f2bf(bL[p][0].x); g0.h[1] = f2bf(bL[p][0].y);
      g0.h[2] = f2bf(bL[p][0].z); g0.h[3] = f2bf(bL[p][0].w);
      g0.h[4] = f2bf(bL[p][1].x); g0.h[5] = f2bf(bL[p][1].y);
      g0.h[6] = f2bf(bL[p][1].z); g0.h[7] = f2bf(bL[p][1].w);
      g1.h[0] = f2bf(bL[p][2].x); g1.h[1] = f2bf(bL[p][2].y);
      g1.h[2] = f2bf(bL[p][2].z); g1.h[3] = f2bf(bL[p][2].w);
      g1.h[4] = f2bf(bL[p][3].x); g1.h[5] = f2bf(bL[p][3].y);
      g1.h[6] = f2bf(bL[p][3].z); g1.h[7] = f2bf(bL[p][3].w);
      int s0 = (bc >> 3) ^ (row & 7);
      int s1 = ((bc >> 3) + 1) ^ (row & 7);
      *(uint4*)((char*)lB[nb] + row * 128 + s0 * 16) = g0.v;
      *(uint4*)((char*)lB[nb] + row * 128 + s1 * 16) = g1.v;
    }
  };

  auto COMPUTE = [&](int cb) {
#pragma unroll
    for (int ks = 0; ks < 2; ++ks) {
      int kg = lane >> 4;
      int rlo = lane & 15;
      int slot = ks * 4 + kg;
      bf16x8 af[4], bfr[4];
#pragma unroll
      for (int fm = 0; fm < 4; ++fm) {
        int row = wm * 64 + fm * 16 + rlo;
        af[fm] = *(const bf16x8*)((char*)lA[cb] + row * 128 + ((slot ^ (row & 7)) * 16));
      }
#pragma unroll
      for (int fn = 0; fn < 4; ++fn) {
        int row = wn * 64 + fn * 16 + rlo;
        bfr[fn] = *(const bf16x8*)((char*)lB[cb] + row * 128 + ((slot ^ (row & 7)) * 16));
      }
#pragma unroll
      for (int fm = 0; fm < 4; ++fm)
#pragma unroll
        for (int fn = 0; fn < 4; ++fn)
          acc[fm][fn] = __builtin_amdgcn_mfma_f32_16x16x32_bf16(af[fm], bfr[fn],
                                                                acc[fm][fn], 0, 0, 0);
    }
  };

  LOAD(0);
  STORE(0);
  __syncthreads();
  for (int c = 0; c < 8; ++c) {
    int cb = c & 1, nb = cb ^ 1;
    if (c < 7) LOAD(c + 1);    // issue global loads early (latency under MFMA)
    COMPUTE(cb);
    if (c < 7) STORE(nb);      // cvt + ds_write into other buffer
    __syncthreads();
  }

  // epilogue: C/D layout col = lane&15, row = (lane>>4)*4 + j  (m89-verified)
  int rlo = lane & 15, rhi = lane >> 4;
#pragma unroll
  for (int fm = 0; fm < 4; ++fm)
#pragma unroll
    for (int fn = 0; fn < 4; ++fn)
#pragma unroll
      for (int j = 0; j < 4; ++j) {
        int b_ = wm * 64 + fm * 16 + rhi * 4 + j;
        int h_ = ht * 128 + wn * 64 + fn * 16 + rlo;
        unsafeAtomicAdd(&yp[b_ * Hh + h_], acc[fm][fn][j]);
      }
}

// ---------------------------------------------------------------- combine
__global__ __launch_bounds__(256) void combine_kernel(
    const float* __restrict__ hprev, const float* __restrict__ u,
    const float* __restrict__ bxr, const float* __restrict__ bxz,
    const float* __restrict__ bxn, const float* __restrict__ brh,
    const float* __restrict__ bzh, const float* __restrict__ bnh,
    const float* __restrict__ yx, const float* __restrict__ dW,
    float* __restrict__ out)
{
  int b = blockIdx.x;  // 128
  __shared__ float su[KE];
  if (threadIdx.x < KE) su[threadIdx.x] = u[b * KE + threadIdx.x];
  __syncthreads();
  for (int h = threadIdx.x; h < Hh; h += 256) {
    float m_r = 0.f, m_z = 0.f, m_bxn = 0.f, m_bnh = 0.f;
    float d_r = 0.f, d_z = 0.f, d_n = 0.f;
#pragma unroll
    for (int k = 0; k < KE; ++k) {
      float uk = su[k];
      int i = k * Hh + h;
      m_r   += uk * (bxr[i] + brh[i]);
      m_z   += uk * (bxz[i] + bzh[i]);
      m_bxn += uk * bxn[i];
      m_bnh += uk * bnh[i];
      d_r   += uk * dW[0 * KE * Hh + i];
      d_z   += uk * dW[1 * KE * Hh + i];
      d_n   += uk * dW[2 * KE * Hh + i];
    }
    float hp = hprev[b * Hh + h];
    float pr = yx[0 * Bb * Hh + b * Hh + h] + m_r + d_r * hp;
    float pz = yx[1 * Bb * Hh + b * Hh + h] + m_z + d_z * hp;
    float r = 1.f / (1.f + expf(-pr));
    float z = 1.f / (1.f + expf(-pz));
    float pn = yx[2 * Bb * Hh + b * Hh + h] + m_bxn + r * (d_n * hp + m_bnh);
    float n = tanhf(pn);
    out[b * Hh + h] = (1.f - z) * n + z * hp;
  }
}

// ---------------------------------------------------------------- launch
extern "C" void kernel_launch(void* const* d_in, const int* in_sizes, int n_in,
                              void* d_out, int out_size, void* d_ws, size_t ws_size,
                              hipStream_t stream) {
  const float* x   = (const float*)d_in[0];
  const float* hp  = (const float*)d_in[1];
  const float* u   = (const float*)d_in[2];
  const float* Wxr = (const float*)d_in[3];
  const float* Wxz = (const float*)d_in[4];
  const float* Wxn = (const float*)d_in[5];
  const float* Whr = (const float*)d_in[6];
  const float* Whz = (const float*)d_in[7];
  const float* Whn = (const float*)d_in[8];
  const float* bxr = (const float*)d_in[9];
  const float* bxz = (const float*)d_in[10];
  const float* bxn = (const float*)d_in[11];
  const float* brh = (const float*)d_in[12];
  const float* bzh = (const float*)d_in[13];
  const float* bnh = (const float*)d_in[14];
  float* out = (float*)d_out;

  u16* xu   = (u16*)d_ws;                                        // 2 MB
  float* yx = (float*)((char*)d_ws + 2 * 1024 * 1024);           // 768 KB
  float* dW = (float*)((char*)d_ws + 2 * 1024 * 1024 + 786432);  // 96 KB

  prep_kernel<<<800, 256, 0, stream>>>(x, u, Whr, Whz, Whn, xu, yx, dW);
  gemm_kernel<<<192, 256, 0, stream>>>(Wxr, Wxz, Wxn, xu, yx);
  combine_kernel<<<128, 256, 0, stream>>>(hp, u, bxr, bxz, bxn, brh, bzh, bnh,
                                          yx, dW, out);
}

// Round 3
// 165.397 us; speedup vs baseline: 1.0270x; 1.0270x over previous
//
#include <hip/hip_runtime.h>
#include <cstdint>
#include <cstddef>

#define Bb 128
#define Dd 512
#define Hh 512
#define KE 16

typedef unsigned short u16;
typedef __bf16 bf16x8 __attribute__((ext_vector_type(8)));
typedef float f32x4 __attribute__((ext_vector_type(4)));

union U8 { __bf16 h[8]; uint4 v; };

// ---------------------------------------------------------------- gemm
// grid = 192: bid = ((ht*3 + bank)<<4) | k  (k in low bits -> same-k blocks
// share an XCD so the x re-reads stay L2-local).  Block tile: M=128(b) x
// N=128(h), contraction D=512 in 8 chunks of 64.  4 waves, 64x64 wave tiles,
// mfma_f32_16x16x32_bf16, double-buffered LDS with XOR-16B swizzle.
// A-operand = bf16(u[b,k]*x[b,d]) computed on the fly at stage time.
// Also extracts this block's 128 Wh-diagonal elements (h-path needs only
// the diagonal of the mixed weight).
__global__ __launch_bounds__(256) void gemm_kernel(
    const float* __restrict__ Wxr, const float* __restrict__ Wxz,
    const float* __restrict__ Wxn,
    const float* __restrict__ Whr, const float* __restrict__ Whz,
    const float* __restrict__ Whn,
    const float* __restrict__ x, const float* __restrict__ u,
    float* __restrict__ yx, float* __restrict__ dW)
{
  int bid = blockIdx.x;
  int k = bid & 15;
  int rem = bid >> 4;          // 0..11
  int bank = rem % 3;
  int ht = rem / 3;            // 0..3

  const float* Wp = (bank == 0 ? Wxr : (bank == 1 ? Wxz : Wxn))
                    + (size_t)k * Hh * Dd + (size_t)ht * 128 * Dd;
  const float* Whp = (bank == 0 ? Whr : (bank == 1 ? Whz : Whn));
  float* yp = yx + bank * Bb * Hh;

  int tid = threadIdx.x;

  // diagonal extraction: each block owns dW[bank][k][ht*128 .. ht*128+128)
  if (tid < 128) {
    int h = ht * 128 + tid;
    dW[(bank * KE + k) * Hh + h] =
        Whp[(size_t)k * Hh * Hh + (size_t)h * (Hh + 1)];
  }

  __shared__ __align__(16) u16 lA[2][128 * 64];   // 16KB x2
  __shared__ __align__(16) u16 lB[2][128 * 64];   // 16KB x2

  int lane = tid & 63;
  int wave = tid >> 6;
  int wm = wave >> 1;
  int wn = wave & 1;

  // staging maps
  int ar = tid >> 1;            // 0..127 (b row)
  int acf = (tid & 1) * 32;     // 0 / 32  (f32 elems within 64-chunk)
  int br = tid >> 2;            // 0..63   (h row)
  int bcf = (tid & 3) * 16;     // 0/16/32/48 (f32 elems)

  float uk = u[ar * KE + k];    // per-thread row scale for A

  float4 aL[8];
  float4 bL[8];

  f32x4 acc[4][4];
#pragma unroll
  for (int i = 0; i < 4; ++i)
#pragma unroll
    for (int j = 0; j < 4; ++j) acc[i][j] = (f32x4){0.f, 0.f, 0.f, 0.f};

  auto LOAD = [&](int c) {
    int d0 = c * 64;
#pragma unroll
    for (int q = 0; q < 8; ++q)
      aL[q] = *(const float4*)(x + ar * Dd + d0 + acf + 4 * q);
#pragma unroll
    for (int p = 0; p < 2; ++p)
#pragma unroll
      for (int q = 0; q < 4; ++q)
        bL[p * 4 + q] =
            *(const float4*)(Wp + (br + 64 * p) * Dd + d0 + bcf + 4 * q);
  };

  auto STORE = [&](int nb) {
#pragma unroll
    for (int q = 0; q < 4; ++q) {
      U8 o;
      const float* f0 = (const float*)&aL[2 * q];
      const float* f1 = (const float*)&aL[2 * q + 1];
#pragma unroll
      for (int j = 0; j < 4; ++j) {
        o.h[j]     = (__bf16)(uk * f0[j]);
        o.h[4 + j] = (__bf16)(uk * f1[j]);
      }
      int slot = ((acf >> 3) + q) ^ (ar & 7);
      *(uint4*)((char*)lA[nb] + ar * 128 + slot * 16) = o.v;
    }
#pragma unroll
    for (int p = 0; p < 2; ++p) {
      int row = br + 64 * p;
      U8 g0, g1;
      const float* c0 = (const float*)&bL[p * 4 + 0];
      const float* c1 = (const float*)&bL[p * 4 + 1];
      const float* c2 = (const float*)&bL[p * 4 + 2];
      const float* c3 = (const float*)&bL[p * 4 + 3];
#pragma unroll
      for (int j = 0; j < 4; ++j) {
        g0.h[j]     = (__bf16)c0[j];
        g0.h[4 + j] = (__bf16)c1[j];
        g1.h[j]     = (__bf16)c2[j];
        g1.h[4 + j] = (__bf16)c3[j];
      }
      int s0 = (bcf >> 3) ^ (row & 7);
      int s1 = ((bcf >> 3) + 1) ^ (row & 7);
      *(uint4*)((char*)lB[nb] + row * 128 + s0 * 16) = g0.v;
      *(uint4*)((char*)lB[nb] + row * 128 + s1 * 16) = g1.v;
    }
  };

  auto COMPUTE = [&](int cb) {
    int kg = lane >> 4;
    int rlo = lane & 15;
#pragma unroll
    for (int ks = 0; ks < 2; ++ks) {
      int slot = ks * 4 + kg;
      bf16x8 af[4], bfr[4];
#pragma unroll
      for (int fm = 0; fm < 4; ++fm) {
        int row = wm * 64 + fm * 16 + rlo;
        af[fm] = *(const bf16x8*)((char*)lA[cb] + row * 128 +
                                  ((slot ^ (row & 7)) * 16));
      }
#pragma unroll
      for (int fn = 0; fn < 4; ++fn) {
        int row = wn * 64 + fn * 16 + rlo;
        bfr[fn] = *(const bf16x8*)((char*)lB[cb] + row * 128 +
                                   ((slot ^ (row & 7)) * 16));
      }
#pragma unroll
      for (int fm = 0; fm < 4; ++fm)
#pragma unroll
        for (int fn = 0; fn < 4; ++fn)
          acc[fm][fn] = __builtin_amdgcn_mfma_f32_16x16x32_bf16(
              af[fm], bfr[fn], acc[fm][fn], 0, 0, 0);
    }
  };

  LOAD(0);
  STORE(0);
  __syncthreads();
  for (int c = 0; c < 8; ++c) {
    int cb = c & 1, nb = cb ^ 1;
    if (c < 7) LOAD(c + 1);    // issue next chunk's global loads early
    COMPUTE(cb);
    if (c < 7) STORE(nb);      // cvt + ds_write into other buffer
    __syncthreads();
  }

  // epilogue: C/D layout col = lane&15, row = (lane>>4)*4 + j  (m89-verified)
  int rlo = lane & 15, rhi = lane >> 4;
#pragma unroll
  for (int fm = 0; fm < 4; ++fm)
#pragma unroll
    for (int fn = 0; fn < 4; ++fn)
#pragma unroll
      for (int j = 0; j < 4; ++j) {
        int b_ = wm * 64 + fm * 16 + rhi * 4 + j;
        int h_ = ht * 128 + wn * 64 + fn * 16 + rlo;
        unsafeAtomicAdd(&yp[b_ * Hh + h_], acc[fm][fn][j]);
      }
}

// ---------------------------------------------------------------- combine
__global__ __launch_bounds__(256) void combine_kernel(
    const float* __restrict__ hprev, const float* __restrict__ u,
    const float* __restrict__ bxr, const float* __restrict__ bxz,
    const float* __restrict__ bxn, const float* __restrict__ brh,
    const float* __restrict__ bzh, const float* __restrict__ bnh,
    const float* __restrict__ yx, const float* __restrict__ dW,
    float* __restrict__ out)
{
  int b = blockIdx.x;  // 128
  __shared__ float su[KE];
  if (threadIdx.x < KE) su[threadIdx.x] = u[b * KE + threadIdx.x];
  __syncthreads();
  for (int h = threadIdx.x; h < Hh; h += 256) {
    float m_r = 0.f, m_z = 0.f, m_bxn = 0.f, m_bnh = 0.f;
    float d_r = 0.f, d_z = 0.f, d_n = 0.f;
#pragma unroll
    for (int k = 0; k < KE; ++k) {
      float uk = su[k];
      int i = k * Hh + h;
      m_r   += uk * (bxr[i] + brh[i]);
      m_z   += uk * (bxz[i] + bzh[i]);
      m_bxn += uk * bxn[i];
      m_bnh += uk * bnh[i];
      d_r   += uk * dW[0 * KE * Hh + i];
      d_z   += uk * dW[1 * KE * Hh + i];
      d_n   += uk * dW[2 * KE * Hh + i];
    }
    float hp = hprev[b * Hh + h];
    float pr = yx[0 * Bb * Hh + b * Hh + h] + m_r + d_r * hp;
    float pz = yx[1 * Bb * Hh + b * Hh + h] + m_z + d_z * hp;
    float r = 1.f / (1.f + expf(-pr));
    float z = 1.f / (1.f + expf(-pz));
    float pn = yx[2 * Bb * Hh + b * Hh + h] + m_bxn + r * (d_n * hp + m_bnh);
    float n = tanhf(pn);
    out[b * Hh + h] = (1.f - z) * n + z * hp;
  }
}

// ---------------------------------------------------------------- launch
extern "C" void kernel_launch(void* const* d_in, const int* in_sizes, int n_in,
                              void* d_out, int out_size, void* d_ws, size_t ws_size,
                              hipStream_t stream) {
  const float* x   = (const float*)d_in[0];
  const float* hp  = (const float*)d_in[1];
  const float* u   = (const float*)d_in[2];
  const float* Wxr = (const float*)d_in[3];
  const float* Wxz = (const float*)d_in[4];
  const float* Wxn = (const float*)d_in[5];
  const float* Whr = (const float*)d_in[6];
  const float* Whz = (const float*)d_in[7];
  const float* Whn = (const float*)d_in[8];
  const float* bxr = (const float*)d_in[9];
  const float* bxz = (const float*)d_in[10];
  const float* bxn = (const float*)d_in[11];
  const float* brh = (const float*)d_in[12];
  const float* bzh = (const float*)d_in[13];
  const float* bnh = (const float*)d_in[14];
  float* out = (float*)d_out;

  float* yx = (float*)d_ws;                          // 3*128*512*4 = 768 KB
  float* dW = (float*)((char*)d_ws + 786432);        // 3*16*512*4  =  96 KB

  hipMemsetAsync(yx, 0, 786432, stream);             // zero the accumulators
  gemm_kernel<<<192, 256, 0, stream>>>(Wxr, Wxz, Wxn, Whr, Whz, Whn,
                                       x, u, yx, dW);
  combine_kernel<<<128, 256, 0, stream>>>(hp, u, bxr, bxz, bxn, brh, bzh, bnh,
                                          yx, dW, out);
}